// Round 10
// baseline (111.988 us; speedup 1.0000x reference)
//
#include <hip/hip_runtime.h>
#include <math.h>

// ---------- constants (normalization folded per the reference) ----------
#define SQ15f      3.8729833462074170f   // sqrt(15)
#define C2_XZ      1.7320508075688772f   // sqrt(3)
#define C2_ZX      0.8660254037844386f   // sqrt(3)/2
#define C3_A       0.4082482904638631f   // 1/sqrt(6)
#define C3_B       0.6123724356957945f   // sqrt(24)/8
#define EMB_SCALE  2.8234622000789103f   // sqrt(10)/1.12

#define NT 8   // tiles (of 256 edges) per block

typedef float v2f __attribute__((ext_vector_type(2)));
typedef float v4f __attribute__((ext_vector_type(4)));

// Raw barrier: orders LDS (lgkmcnt) + workgroup sync WITHOUT draining vmcnt,
// so in-flight nontemporal stores keep retiring during the next tile's compute.
__device__ __forceinline__ void lds_barrier() {
    asm volatile("s_waitcnt lgkmcnt(0)\n\ts_barrier" ::: "memory");
    __builtin_amdgcn_sched_barrier(0);
}

__device__ __forceinline__ void edge_compute(const float* __restrict__ pos,
                                             const float* __restrict__ qpos,
                                             int s, int d,
                                             float em[10], float sh[16], float& len) {
    float vx = qpos[3 * s + 0] - pos[3 * d + 0];
    float vy = qpos[3 * s + 1] - pos[3 * d + 1];
    float vz = qpos[3 * s + 2] - pos[3 * d + 2];

    float ss  = vx * vx + vy * vy + vz * vz;
    len = sqrtf(ss + 1e-8f);

    float n   = sqrtf(ss);
    float inv = 1.0f / fmaxf(n, 1e-12f);
    float x = vx * inv, y = vy * inv, z = vz * inv;

    float x2 = x * x, y2 = y * y, z2 = z * z;
    float x2z2 = x2 + z2;

    float s20 = SQ15f * x * z;
    float s24 = 0.5f * SQ15f * (z2 - x2);
    float q   = 4.0f * y2 - x2z2;

    sh[0] = 1.0f;
    sh[1] = x;  sh[2] = y;  sh[3] = z;
    sh[4] = C2_XZ * x * z;
    sh[5] = C2_XZ * x * y;
    sh[6] = y2 - 0.5f * x2z2;
    sh[7] = C2_XZ * y * z;
    sh[8] = C2_ZX * (z2 - x2);
    sh[9]  = C3_A * (s20 * z + s24 * x);
    sh[10] = s20 * y;
    sh[11] = C3_B * q * x;
    sh[12] = 0.5f * y * (2.0f * y2 - 3.0f * x2z2);
    sh[13] = C3_B * z * q;
    sh[14] = s24 * y;
    sh[15] = C3_A * (s24 * z - s20 * x);

    float t = (0.2f - len) * 5.5f;
    float cut;
    if (t <= 0.0f)      cut = 1.0f;
    else if (t >= 1.0f) cut = 0.0f;
    else {
        float t2 = t * t;
        float t4 = t2 * t2;
        cut = 1.0f - (5.0f * t4 - 4.0f * t4 * t);
    }
    float cs = cut * EMB_SCALE;

#pragma unroll
    for (int i = 0; i < 10; ++i) {
        float m  = (9.0f + 8.0f * (float)i) * (1.0f / 81.0f);
        float dd = (len - m) * 9.0f;
        em[i] = __expf(-dd * dd) * cs;
    }
}

// sh LDS layout: logical in-block float g (0..4095) at ssh[g + (g>>4)]
// (row-major [256][16] pad-17: conflict-free writes and v4f reads).
// emb LDS: linear [2560].
__device__ __forceinline__ void bulk_store(const float* __restrict__ semb,
                                           const float* __restrict__ ssh,
                                           float* __restrict__ egb,
                                           float* __restrict__ sgb,
                                           int tid, int nb) {
    if (nb == 256) {
#pragma unroll
        for (int i = 0; i < 3; ++i) {
            int idx = i * 256 + tid;
            if (idx < 639) {
                int p = 2 + 4 * idx;
                v4f v = { semb[p], semb[p + 1], semb[p + 2], semb[p + 3] };
                __builtin_nontemporal_store(v, (v4f*)(egb + p));
            }
        }
        if (tid == 0) { v2f h = { semb[0], semb[1] };        __builtin_nontemporal_store(h, (v2f*)egb); }
        if (tid == 1) { v2f tl = { semb[2558], semb[2559] }; __builtin_nontemporal_store(tl, (v2f*)(egb + 2558)); }

#pragma unroll
        for (int i = 0; i < 4; ++i) {
            int idx = i * 256 + tid;
            if (idx < 1023) {
                int g0 = 2 + 4 * idx;
                v4f v = { ssh[g0 + (g0 >> 4)],
                          ssh[(g0 + 1) + ((g0 + 1) >> 4)],
                          ssh[(g0 + 2) + ((g0 + 2) >> 4)],
                          ssh[(g0 + 3) + ((g0 + 3) >> 4)] };
                __builtin_nontemporal_store(v, (v4f*)(sgb + g0));
            }
        }
        if (tid == 2) { v2f h = { ssh[0], ssh[1] };           __builtin_nontemporal_store(h, (v2f*)sgb); }
        if (tid == 3) { v2f tl = { ssh[4349], ssh[4350] };    __builtin_nontemporal_store(tl, (v2f*)(sgb + 4094)); }
    } else {
        for (int k = tid; k < nb * 10; k += 256)
            __builtin_nontemporal_store(semb[k], egb + k);
        for (int k = tid; k < nb * 16; k += 256)
            __builtin_nontemporal_store(ssh[k + (k >> 4)], sgb + k);
    }
}

__global__ __launch_bounds__(256)
void fused_kernel(const float* __restrict__ pos,
                  const float* __restrict__ qpos,
                  const float* __restrict__ feat,
                  const int*   __restrict__ esrc,
                  const int*   __restrict__ edst,
                  float* __restrict__ out,
                  int E, int nblk_edge, int n2feat,
                  unsigned long long OFF_SRC, unsigned long long OFF_DST,
                  unsigned long long OFF_EMB, unsigned long long OFF_SH,
                  unsigned long long OFF_LEN) {
    const int tid = threadIdx.x;
    const int blk = blockIdx.x;

    if (blk >= nblk_edge) {                 // ---- feature passthrough blocks ----
        int i = (blk - nblk_edge) * 256 + tid;
        if (i == 0) { out[0] = 10.0f; out[1] = 1000.0f; }   // Nt, Ny
        if (i < n2feat) {
            v2f v = __builtin_nontemporal_load(((const v2f*)feat) + i);
            __builtin_nontemporal_store(v, ((v2f*)(out + 2)) + i);
        }
        return;
    }

    __shared__ float semb[2560];
    __shared__ float ssh [4352];

    float em[10], sh[16], len;
    int s = 0, d = 0;

    // ---- prologue: tile 0 indices + compute into registers ----
    {
        int tb = blk * NT * 256;
        if (tb < E) {
            int nb = min(256, E - tb);
            if (tid < nb) {
                s = __builtin_nontemporal_load(esrc + tb + tid);
                d = __builtin_nontemporal_load(edst + tb + tid);
                edge_compute(pos, qpos, s, d, em, sh, len);
            }
        }
    }

    for (int t = 0; t < NT; ++t) {
        const int tb = (blk * NT + t) * 256;
        if (tb >= E) break;
        const int nb = min(256, E - tb);
        const int e  = tb + tid;

        // scalar streams + stage current tile into LDS
        if (tid < nb) {
            __builtin_nontemporal_store((float)s, out + OFF_SRC + e);
            __builtin_nontemporal_store((float)d, out + OFF_DST + e);
            __builtin_nontemporal_store(len,      out + OFF_LEN + e);
            float* emp = &semb[tid * 10];
#pragma unroll
            for (int j = 0; j < 10; ++j) emp[j] = em[j];
            float* shp = &ssh[tid * 17];
#pragma unroll
            for (int c = 0; c < 16; ++c) shp[c] = sh[c];
        }

        lds_barrier();   // staging visible; nt stores NOT drained

        // prefetch next tile's indices early (latency hides under store issue)
        const int tb2 = tb + 256;
        const bool has2 = (t + 1 < NT) && (tb2 < E);
        int s2 = 0, d2 = 0, nb2 = 0;
        if (has2) {
            nb2 = min(256, E - tb2);
            if (tid < nb2) {
                s2 = __builtin_nontemporal_load(esrc + tb2 + tid);
                d2 = __builtin_nontemporal_load(edst + tb2 + tid);
            }
        }

        // BW phase: stream current tile from LDS to HBM (nontemporal)
        bulk_store(semb, ssh, out + OFF_EMB + 10ULL * (unsigned long long)tb,
                   out + OFF_SH + 16ULL * (unsigned long long)tb, tid, nb);

        // overlap: next tile's gathers + compute while stores drain
        if (has2 && tid < nb2) {
            edge_compute(pos, qpos, s2, d2, em, sh, len);
            s = s2; d = d2;
        }

        lds_barrier();   // all LDS reads done before next staging overwrites
    }
}

extern "C" void kernel_launch(void* const* d_in, const int* in_sizes, int n_in,
                              void* d_out, int out_size, void* d_ws, size_t ws_size,
                              hipStream_t stream) {
    const float* pos  = (const float*)d_in[0];
    const float* qpos = (const float*)d_in[1];
    const float* feat = (const float*)d_in[2];
    const int*   esrc = (const int*)d_in[3];
    const int*   edst = (const int*)d_in[4];
    float* out = (float*)d_out;

    const int Ftot = in_sizes[2];   // 320000
    const int E    = in_sizes[3];   // 3000000

    const unsigned long long OFF_FEAT = 2;
    const unsigned long long OFF_SRC  = OFF_FEAT + (unsigned long long)Ftot;
    const unsigned long long OFF_DST  = OFF_SRC + (unsigned long long)E;
    const unsigned long long OFF_EMB  = OFF_DST + (unsigned long long)E;
    const unsigned long long OFF_SH   = OFF_EMB + 10ULL * E;
    const unsigned long long OFF_LEN  = OFF_SH  + 16ULL * E;

    const int n2feat    = Ftot / 2;
    const int ntiles    = (E + 255) / 256;
    const int nblk_edge = (ntiles + NT - 1) / NT;
    const int nblk_feat = (n2feat + 255) / 256;

    fused_kernel<<<nblk_edge + nblk_feat, 256, 0, stream>>>(
        pos, qpos, feat, esrc, edst, out,
        E, nblk_edge, n2feat, OFF_SRC, OFF_DST, OFF_EMB, OFF_SH, OFF_LEN);
}

// Round 11
// 97.272 us; speedup vs baseline: 1.1513x; 1.1513x over previous
//
#include <hip/hip_runtime.h>
#include <math.h>

// ---------- constants (normalization folded per the reference) ----------
#define SQ15f      3.8729833462074170f   // sqrt(15)
#define C2_XZ      1.7320508075688772f   // sqrt(3)
#define C2_ZX      0.8660254037844386f   // sqrt(3)/2
#define C3_A       0.4082482904638631f   // 1/sqrt(6)
#define C3_B       0.6123724356957945f   // sqrt(24)/8
#define EMB_SCALE  2.8234622000789103f   // sqrt(10)/1.12

typedef float v2f __attribute__((ext_vector_type(2)));
typedef float v4f __attribute__((ext_vector_type(4)));

// Per-WAVE scratch, zero barriers (intra-wave DS ops are in-order).
//   emb: logical p in [0,640)  -> wb[p + (p>>4)]          (max 678)
//   sh : logical q in [0,1024) -> wb[SOFF + q + (q>>4)]   (max SOFF+1086)
// pad-every-16 keeps both the stride-10/17 row writes (<=2-way) and the
// stride-4 v4f cooperative reads (exactly 2/bank = free) conflict-light.
#define SOFF 680
#define WSCR 1768

__global__ __launch_bounds__(256)
void fused_kernel(const float* __restrict__ pos,
                  const float* __restrict__ qpos,
                  const float* __restrict__ feat,
                  const int*   __restrict__ esrc,
                  const int*   __restrict__ edst,
                  float* __restrict__ out,
                  int E, int nblk_edge, int n2feat,
                  unsigned long long OFF_SRC, unsigned long long OFF_DST,
                  unsigned long long OFF_EMB, unsigned long long OFF_SH,
                  unsigned long long OFF_LEN) {
    const int tid = threadIdx.x;
    const int blk = blockIdx.x;

    if (blk >= nblk_edge) {                 // ---- feature passthrough blocks ----
        int i = (blk - nblk_edge) * 256 + tid;
        if (i == 0) { out[0] = 10.0f; out[1] = 1000.0f; }   // Nt, Ny
        if (i < n2feat) {
            v2f v = __builtin_nontemporal_load(((const v2f*)feat) + i);
            __builtin_nontemporal_store(v, ((v2f*)(out + 2)) + i);
        }
        return;
    }

    __shared__ float scr[4 * WSCR];
    const int lane = tid & 63;
    const int wv   = tid >> 6;
    float* wb = &scr[wv * WSCR];

    // E % 64 == 0 for this problem (3,000,000 / 64 = 46875): every wave chunk
    // is full. Guard anyway for generality (whole-wave uniform exit, no barrier).
    const long long cb = ((long long)blk * 4 + wv) * 64;
    if (cb >= E) return;
    const long long e = cb + lane;
    const bool full = (cb + 64 <= E);
    const bool act  = full || (e < E);

    float em[10], sh[16], len = 0.0f;
    int s = 0, d = 0;

    if (act) {
        s = __builtin_nontemporal_load(esrc + e);
        d = __builtin_nontemporal_load(edst + e);

        float vx = qpos[3 * s + 0] - pos[3 * d + 0];
        float vy = qpos[3 * s + 1] - pos[3 * d + 1];
        float vz = qpos[3 * s + 2] - pos[3 * d + 2];

        float ss  = vx * vx + vy * vy + vz * vz;
        len = sqrtf(ss + 1e-8f);

        float n   = sqrtf(ss);
        float inv = 1.0f / fmaxf(n, 1e-12f);
        float x = vx * inv, y = vy * inv, z = vz * inv;

        float x2 = x * x, y2 = y * y, z2 = z * z;
        float x2z2 = x2 + z2;

        float s20 = SQ15f * x * z;
        float s24 = 0.5f * SQ15f * (z2 - x2);
        float q   = 4.0f * y2 - x2z2;

        sh[0] = 1.0f;
        sh[1] = x;  sh[2] = y;  sh[3] = z;
        sh[4] = C2_XZ * x * z;
        sh[5] = C2_XZ * x * y;
        sh[6] = y2 - 0.5f * x2z2;
        sh[7] = C2_XZ * y * z;
        sh[8] = C2_ZX * (z2 - x2);
        sh[9]  = C3_A * (s20 * z + s24 * x);
        sh[10] = s20 * y;
        sh[11] = C3_B * q * x;
        sh[12] = 0.5f * y * (2.0f * y2 - 3.0f * x2z2);
        sh[13] = C3_B * z * q;
        sh[14] = s24 * y;
        sh[15] = C3_A * (s24 * z - s20 * x);

        float t = (0.2f - len) * 5.5f;
        float cut;
        if (t <= 0.0f)      cut = 1.0f;
        else if (t >= 1.0f) cut = 0.0f;
        else {
            float t2 = t * t;
            float t4 = t2 * t2;
            cut = 1.0f - (5.0f * t4 - 4.0f * t4 * t);
        }
        float cs = cut * EMB_SCALE;

#pragma unroll
        for (int i = 0; i < 10; ++i) {
            float m  = (9.0f + 8.0f * (float)i) * (1.0f / 81.0f);
            float dd = (len - m) * 9.0f;
            em[i] = __expf(-dd * dd) * cs;
        }

        // coalesced 4 B/lane streams
        __builtin_nontemporal_store((float)s, out + OFF_SRC + e);
        __builtin_nontemporal_store((float)d, out + OFF_DST + e);
        __builtin_nontemporal_store(len,      out + OFF_LEN + e);
    }

    if (full) {
        // ---- stage this wave's 64 edges into private scratch ----
#pragma unroll
        for (int j = 0; j < 10; ++j) { int p = lane * 10 + j; wb[p + (p >> 4)] = em[j]; }
#pragma unroll
        for (int c = 0; c < 16; ++c) { wb[SOFF + lane * 17 + c] = sh[c]; }
        // (compiler orders DS read-after-write within the wave via lgkmcnt)

        // ---- stream out: emb span = 640 floats, start ≡ 2 (mod 4) ----
        float* ge = out + OFF_EMB + 10ULL * (unsigned long long)cb;
        float* gs = out + OFF_SH  + 16ULL * (unsigned long long)cb;

        if (lane == 0) { v2f h = { wb[0], wb[1] };
                         __builtin_nontemporal_store(h, (v2f*)ge); }
        if (lane == 1) { v2f t = { wb[638 + (638 >> 4)], wb[639 + (639 >> 4)] };
                         __builtin_nontemporal_store(t, (v2f*)(ge + 638)); }
#pragma unroll
        for (int it = 0; it < 3; ++it) {
            int i = it * 64 + lane;
            if (i < 159) {
                int p0 = 2 + 4 * i;
                v4f v = { wb[p0     + (p0 >> 4)],
                          wb[p0 + 1 + ((p0 + 1) >> 4)],
                          wb[p0 + 2 + ((p0 + 2) >> 4)],
                          wb[p0 + 3 + ((p0 + 3) >> 4)] };
                __builtin_nontemporal_store(v, (v4f*)(ge + p0));
            }
        }

        // ---- sh span = 1024 floats, start ≡ 2 (mod 4) ----
        if (lane == 2) { v2f h = { wb[SOFF + 0], wb[SOFF + 1] };
                         __builtin_nontemporal_store(h, (v2f*)gs); }
        if (lane == 3) { v2f t = { wb[SOFF + 1022 + (1022 >> 4)], wb[SOFF + 1023 + (1023 >> 4)] };
                         __builtin_nontemporal_store(t, (v2f*)(gs + 1022)); }
#pragma unroll
        for (int it = 0; it < 4; ++it) {
            int i = it * 64 + lane;
            if (i < 255) {
                int p0 = 2 + 4 * i;
                v4f v = { wb[SOFF + p0     + (p0 >> 4)],
                          wb[SOFF + p0 + 1 + ((p0 + 1) >> 4)],
                          wb[SOFF + p0 + 2 + ((p0 + 2) >> 4)],
                          wb[SOFF + p0 + 3 + ((p0 + 3) >> 4)] };
                __builtin_nontemporal_store(v, (v4f*)(gs + p0));
            }
        }
    } else if (act) {
        // partial wave (not hit for E%64==0): per-lane direct stores
        float* ge = out + OFF_EMB + 10ULL * (unsigned long long)e;
        float* gs = out + OFF_SH  + 16ULL * (unsigned long long)e;
#pragma unroll
        for (int j = 0; j < 10; ++j) __builtin_nontemporal_store(em[j], ge + j);
#pragma unroll
        for (int c = 0; c < 16; ++c) __builtin_nontemporal_store(sh[c], gs + c);
    }
}

extern "C" void kernel_launch(void* const* d_in, const int* in_sizes, int n_in,
                              void* d_out, int out_size, void* d_ws, size_t ws_size,
                              hipStream_t stream) {
    const float* pos  = (const float*)d_in[0];
    const float* qpos = (const float*)d_in[1];
    const float* feat = (const float*)d_in[2];
    const int*   esrc = (const int*)d_in[3];
    const int*   edst = (const int*)d_in[4];
    float* out = (float*)d_out;

    const int Ftot = in_sizes[2];   // 320000
    const int E    = in_sizes[3];   // 3000000

    const unsigned long long OFF_FEAT = 2;
    const unsigned long long OFF_SRC  = OFF_FEAT + (unsigned long long)Ftot;
    const unsigned long long OFF_DST  = OFF_SRC + (unsigned long long)E;
    const unsigned long long OFF_EMB  = OFF_DST + (unsigned long long)E;
    const unsigned long long OFF_SH   = OFF_EMB + 10ULL * E;
    const unsigned long long OFF_LEN  = OFF_SH  + 16ULL * E;

    const int n2feat    = Ftot / 2;
    const int nblk_edge = (E + 255) / 256;
    const int nblk_feat = (n2feat + 255) / 256;

    fused_kernel<<<nblk_edge + nblk_feat, 256, 0, stream>>>(
        pos, qpos, feat, esrc, edst, out,
        E, nblk_edge, n2feat, OFF_SRC, OFF_DST, OFF_EMB, OFF_SH, OFF_LEN);
}